// Round 1
// baseline (379.785 us; speedup 1.0000x reference)
//
#include <hip/hip_runtime.h>
#include <hip/hip_bf16.h>
#include <stdint.h>

#define AS_GLOBAL __attribute__((address_space(1)))
#define AS_LDS    __attribute__((address_space(3)))

typedef __attribute__((ext_vector_type(8))) short  bf16x8;
typedef __attribute__((ext_vector_type(4))) float  f32x4;
typedef __attribute__((ext_vector_type(4))) short  s16x4;

__device__ __forceinline__ void gload_lds16(const void* g, void* l) {
    __builtin_amdgcn_global_load_lds((AS_GLOBAL const void*)g, (AS_LDS void*)l, 16, 0, 0);
}

__global__ void cast_f32_bf16_k(const float* __restrict__ s, __hip_bfloat16* __restrict__ d, int n4) {
    int i = blockIdx.x * 256 + threadIdx.x;
    if (i >= n4) return;
    float4 v = ((const float4*)s)[i];
    union { s16x4 p; __hip_bfloat16 h[4]; } u;
    u.h[0] = __float2bfloat16(v.x);
    u.h[1] = __float2bfloat16(v.y);
    u.h[2] = __float2bfloat16(v.z);
    u.h[3] = __float2bfloat16(v.w);
    ((s16x4*)d)[i] = u.p;
}

// C[M,N] = A[M,K] @ B[N,K]^T   (both operands K-major), per-MODE epilogue.
// MODE 0: bf16 C = relu(acc + bias[n])                      (layer 1 -> d1)
// MODE 1: bf16 C = T-step collapse: for t: d2=relu((1-b1^t)*y + b2); s2=b2f(s2,d2); z=b3f(z,s2)
// MODE 2: f32  C = acc + (1 - beta3^T) * bias[n]            (layer 3 -> s3_T)
template <int MODE>
__global__ __launch_bounds__(256, 2)
void gemm_bt(const __hip_bfloat16* __restrict__ A,
             const __hip_bfloat16* __restrict__ Bm,
             void* __restrict__ Cv,
             const int M, const int N, const int K,
             const float* __restrict__ bias,
             const float* __restrict__ b_taus,
             const int* __restrict__ Tp)
{
    __shared__ __hip_bfloat16 As[128 * 32];
    __shared__ __hip_bfloat16 Bs[128 * 32];

    const int tid  = threadIdx.x;
    const int lane = tid & 63;
    const int wave = tid >> 6;       // 0..3
    const int wm   = wave >> 1, wn = wave & 1;
    const int lm   = lane & 15, lq = lane >> 4;

    const int bn = blockIdx.x, bm = blockIdx.y;

    const int crow = lane >> 2;        // row within a 16-row staging chunk
    const int ccol = (lane & 3) * 8;   // bf16 element offset within row (16B granule)

    const __hip_bfloat16* Ag = A  + (size_t)(bm * 128) * K;
    const __hip_bfloat16* Bg = Bm + (size_t)(bn * 128) * K;

    f32x4 acc[4][4];
    #pragma unroll
    for (int i = 0; i < 4; ++i)
        #pragma unroll
        for (int j = 0; j < 4; ++j)
            acc[i][j] = (f32x4){0.f, 0.f, 0.f, 0.f};

    for (int kt = 0; kt < K; kt += 32) {
        __syncthreads();
        #pragma unroll
        for (int c = 0; c < 2; ++c) {
            const int chunk = wave * 2 + c;          // 0..7, wave-uniform
            const int row   = chunk * 16 + crow;
            gload_lds16(Ag + (size_t)row * K + kt + ccol, As + chunk * 512);
            gload_lds16(Bg + (size_t)row * K + kt + ccol, Bs + chunk * 512);
        }
        __syncthreads();
        bf16x8 af[4], bf[4];
        #pragma unroll
        for (int i = 0; i < 4; ++i)
            af[i] = *(const bf16x8*)(As + (wm * 64 + i * 16 + lm) * 32 + lq * 8);
        #pragma unroll
        for (int j = 0; j < 4; ++j)
            bf[j] = *(const bf16x8*)(Bs + (wn * 64 + j * 16 + lm) * 32 + lq * 8);
        #pragma unroll
        for (int i = 0; i < 4; ++i)
            #pragma unroll
            for (int j = 0; j < 4; ++j)
                acc[i][j] = __builtin_amdgcn_mfma_f32_16x16x32_bf16(af[i], bf[j], acc[i][j], 0, 0, 0);
    }

    const int row0 = bm * 128 + wm * 64;
    const int colb = bn * 128 + wn * 64 + lm;

    if constexpr (MODE == 0) {
        __hip_bfloat16* C = (__hip_bfloat16*)Cv;
        #pragma unroll
        for (int j = 0; j < 4; ++j) {
            const int col = colb + j * 16;
            const float bv = bias[col];
            #pragma unroll
            for (int i = 0; i < 4; ++i)
                #pragma unroll
                for (int r = 0; r < 4; ++r) {
                    const int row = row0 + i * 16 + lq * 4 + r;
                    C[(size_t)row * N + col] = __float2bfloat16(fmaxf(acc[i][j][r] + bv, 0.f));
                }
        }
    } else if constexpr (MODE == 1) {
        const int   T   = *Tp;
        const float be1 = 1.f / (1.f + expf(-b_taus[0]));
        const float be2 = 1.f / (1.f + expf(-b_taus[1]));
        const float be3 = 1.f / (1.f + expf(-b_taus[2]));
        __hip_bfloat16* C = (__hip_bfloat16*)Cv;
        #pragma unroll
        for (int j = 0; j < 4; ++j) {
            const int col = colb + j * 16;
            const float bv = bias[col];
            #pragma unroll
            for (int i = 0; i < 4; ++i)
                #pragma unroll
                for (int r = 0; r < 4; ++r) {
                    const int row = row0 + i * 16 + lq * 4 + r;
                    const float y = acc[i][j][r];
                    float p1 = 1.f, s2 = 0.f, za = 0.f;
                    for (int t = 0; t < T; ++t) {
                        p1 *= be1;
                        const float d2 = fmaxf(fmaf(1.f - p1, y, bv), 0.f);
                        s2 = be2 * s2 + (1.f - be2) * d2;
                        za = be3 * za + (1.f - be3) * s2;
                    }
                    C[(size_t)row * N + col] = __float2bfloat16(za);
                }
        }
    } else {
        const int   T   = *Tp;
        const float be3 = 1.f / (1.f + expf(-b_taus[2]));
        float g = 0.f;
        for (int t = 0; t < T; ++t) g = be3 * g + (1.f - be3);   // g = 1 - beta3^T
        float* C = (float*)Cv;
        #pragma unroll
        for (int j = 0; j < 4; ++j) {
            const int col = colb + j * 16;
            const float bv = g * bias[col];
            #pragma unroll
            for (int i = 0; i < 4; ++i)
                #pragma unroll
                for (int r = 0; r < 4; ++r) {
                    const int row = row0 + i * 16 + lq * 4 + r;
                    C[(size_t)row * N + col] = acc[i][j][r] + bv;
                }
        }
    }
}

extern "C" void kernel_launch(void* const* d_in, const int* in_sizes, int n_in,
                              void* d_out, int out_size, void* d_ws, size_t ws_size,
                              hipStream_t stream) {
    const float* x      = (const float*)d_in[0];
    const float* W1     = (const float*)d_in[1];
    const float* b1     = (const float*)d_in[2];
    const float* W2     = (const float*)d_in[3];
    const float* b2     = (const float*)d_in[4];
    const float* W3     = (const float*)d_in[5];
    const float* b3     = (const float*)d_in[6];
    const float* b_taus = (const float*)d_in[7];
    const int*   Tp     = (const int*)d_in[8];

    const int B = 1024, DIN = 2048, H1 = 4096, H2 = 4096, DOUT = 1024;

    char* ws = (char*)d_ws;
    __hip_bfloat16* xb  = (__hip_bfloat16*)ws; ws += (size_t)B * DIN * 2;
    __hip_bfloat16* W1b = (__hip_bfloat16*)ws; ws += (size_t)H1 * DIN * 2;
    __hip_bfloat16* W2b = (__hip_bfloat16*)ws; ws += (size_t)H2 * H1 * 2;
    __hip_bfloat16* W3b = (__hip_bfloat16*)ws; ws += (size_t)DOUT * H2 * 2;
    __hip_bfloat16* D1b = (__hip_bfloat16*)ws; ws += (size_t)B * H1 * 2;
    __hip_bfloat16* Sb  = (__hip_bfloat16*)ws; ws += (size_t)B * H2 * 2;

    auto cast = [&](const float* s, __hip_bfloat16* d, int n) {
        int n4 = n / 4;
        cast_f32_bf16_k<<<dim3((n4 + 255) / 256), dim3(256), 0, stream>>>(s, d, n4);
    };
    cast(x,  xb,  B * DIN);
    cast(W1, W1b, H1 * DIN);
    cast(W2, W2b, H2 * H1);
    cast(W3, W3b, DOUT * H2);

    // Layer 1: D1 = relu(x @ W1^T + b1)           [1024 x 4096]
    gemm_bt<0><<<dim3(H1 / 128, B / 128), 256, 0, stream>>>(xb, W1b, (void*)D1b, B, H1, DIN, b1, nullptr, nullptr);
    // Layer 2 + T-loop: Z = sum_t w_t * s2_t      [1024 x 4096]
    gemm_bt<1><<<dim3(H2 / 128, B / 128), 256, 0, stream>>>(D1b, W2b, (void*)Sb, B, H2, H1, b2, b_taus, Tp);
    // Layer 3: out = Z @ W3^T + (1-b3^T)*b3       [1024 x 1024] fp32
    gemm_bt<2><<<dim3(DOUT / 128, B / 128), 256, 0, stream>>>(Sb, W3b, d_out, B, DOUT, H2, b3, b_taus, Tp);
}

// Round 2
// 279.836 us; speedup vs baseline: 1.3572x; 1.3572x over previous
//
#include <hip/hip_runtime.h>
#include <hip/hip_bf16.h>
#include <stdint.h>

#define AS_GLOBAL __attribute__((address_space(1)))
#define AS_LDS    __attribute__((address_space(3)))

typedef __attribute__((ext_vector_type(8))) short  bf16x8;
typedef __attribute__((ext_vector_type(4))) float  f32x4;
typedef __attribute__((ext_vector_type(4))) short  s16x4;

__device__ __forceinline__ void gload_lds16(const void* g, void* l) {
    __builtin_amdgcn_global_load_lds((AS_GLOBAL const void*)g, (AS_LDS void*)l, 16, 0, 0);
}

// One fused cast kernel: fp32 -> bf16 for x, W1, W2, W3 (exact-cover grid, no tail).
__global__ void cast_all_k(const float* __restrict__ x,  const float* __restrict__ W1,
                           const float* __restrict__ W2, const float* __restrict__ W3,
                           __hip_bfloat16* __restrict__ xb,  __hip_bfloat16* __restrict__ W1b,
                           __hip_bfloat16* __restrict__ W2b, __hip_bfloat16* __restrict__ W3b) {
    const long n0 = 2097152 / 4, n1 = 8388608 / 4, n2 = 16777216 / 4, n3 = 4194304 / 4;
    long i4 = (long)blockIdx.x * 256 + threadIdx.x;   // float4 index
    const float* s; __hip_bfloat16* d; long off;
    if      (i4 < n0)           { s = x;  d = xb;  off = i4; }
    else if (i4 < n0 + n1)      { s = W1; d = W1b; off = i4 - n0; }
    else if (i4 < n0 + n1 + n2) { s = W2; d = W2b; off = i4 - n0 - n1; }
    else                        { s = W3; d = W3b; off = i4 - n0 - n1 - n2; }
    float4 v = ((const float4*)s)[off];
    union { s16x4 p; __hip_bfloat16 h[4]; } u;
    u.h[0] = __float2bfloat16(v.x);
    u.h[1] = __float2bfloat16(v.y);
    u.h[2] = __float2bfloat16(v.z);
    u.h[3] = __float2bfloat16(v.w);
    ((s16x4*)d)[off] = u.p;
}

// Split-K GEMM: P[z][M,N] = A[M, k0:k1] @ B[N, k0:k1]^T  (fp32 partials, no epilogue)
// grid = (N/128, M/128, S), kchunk = K/S. 128x128 tile, 4 waves of 4x4 16x16x32 MFMA.
__global__ __launch_bounds__(256, 2)
void gemm_btk(const __hip_bfloat16* __restrict__ A,
              const __hip_bfloat16* __restrict__ Bm,
              float* __restrict__ P,
              const int M, const int N, const int kchunk)
{
    __shared__ __hip_bfloat16 As[128 * 32];
    __shared__ __hip_bfloat16 Bs[128 * 32];

    const int tid  = threadIdx.x;
    const int lane = tid & 63;
    const int wave = tid >> 6;
    const int wm   = wave >> 1, wn = wave & 1;
    const int lm   = lane & 15, lq = lane >> 4;

    const int bn = blockIdx.x, bm = blockIdx.y, kz = blockIdx.z;
    const int K  = kchunk * gridDim.z;
    const int k0 = kz * kchunk, k1 = k0 + kchunk;

    const int crow = lane >> 2;
    const int ccol = (lane & 3) * 8;

    const __hip_bfloat16* Ag = A  + (size_t)(bm * 128) * K;
    const __hip_bfloat16* Bg = Bm + (size_t)(bn * 128) * K;

    f32x4 acc[4][4];
    #pragma unroll
    for (int i = 0; i < 4; ++i)
        #pragma unroll
        for (int j = 0; j < 4; ++j)
            acc[i][j] = (f32x4){0.f, 0.f, 0.f, 0.f};

    for (int kt = k0; kt < k1; kt += 32) {
        __syncthreads();
        #pragma unroll
        for (int c = 0; c < 2; ++c) {
            const int chunk = wave * 2 + c;
            const int row   = chunk * 16 + crow;
            gload_lds16(Ag + (size_t)row * K + kt + ccol, As + chunk * 512);
            gload_lds16(Bg + (size_t)row * K + kt + ccol, Bs + chunk * 512);
        }
        __syncthreads();
        bf16x8 af[4], bf[4];
        #pragma unroll
        for (int i = 0; i < 4; ++i)
            af[i] = *(const bf16x8*)(As + (wm * 64 + i * 16 + lm) * 32 + lq * 8);
        #pragma unroll
        for (int j = 0; j < 4; ++j)
            bf[j] = *(const bf16x8*)(Bs + (wn * 64 + j * 16 + lm) * 32 + lq * 8);
        #pragma unroll
        for (int i = 0; i < 4; ++i)
            #pragma unroll
            for (int j = 0; j < 4; ++j)
                acc[i][j] = __builtin_amdgcn_mfma_f32_16x16x32_bf16(af[i], bf[j], acc[i][j], 0, 0, 0);
    }

    float* Pz = P + (size_t)kz * M * N;
    const int row0 = bm * 128 + wm * 64;
    const int colb = bn * 128 + wn * 64 + lm;
    #pragma unroll
    for (int j = 0; j < 4; ++j) {
        const int col = colb + j * 16;
        #pragma unroll
        for (int i = 0; i < 4; ++i)
            #pragma unroll
            for (int r = 0; r < 4; ++r) {
                const int row = row0 + i * 16 + lq * 4 + r;
                Pz[(size_t)row * N + col] = acc[i][j][r];
            }
    }
}

// Sum S split-K partials + epilogue.
// MODE 0: bf16 out = relu(sum + bias)            (layer1 -> D1)
// MODE 1: bf16 out = T-collapse(y=sum, b2)       (layer2 -> Z)
// MODE 2: f32  out = sum + (1-beta3^T)*bias      (layer3 -> s3_T)
template <int MODE>
__global__ void reduce_k(const float* __restrict__ P, const int S,
                         void* __restrict__ outv, const long MN, const int N,
                         const float* __restrict__ bias,
                         const float* __restrict__ b_taus,
                         const int* __restrict__ Tp)
{
    long i4 = (long)blockIdx.x * 256 + threadIdx.x;   // float4 index, exact cover
    long i  = i4 * 4;
    float4 a = ((const float4*)P)[i4];
    for (int s = 1; s < S; ++s) {
        float4 b = ((const float4*)(P + (size_t)s * MN))[i4];
        a.x += b.x; a.y += b.y; a.z += b.z; a.w += b.w;
    }
    const int col = (int)(i % N);
    const float4 bv = *(const float4*)(bias + col);

    if constexpr (MODE == 0) {
        union { s16x4 p; __hip_bfloat16 h[4]; } u;
        u.h[0] = __float2bfloat16(fmaxf(a.x + bv.x, 0.f));
        u.h[1] = __float2bfloat16(fmaxf(a.y + bv.y, 0.f));
        u.h[2] = __float2bfloat16(fmaxf(a.z + bv.z, 0.f));
        u.h[3] = __float2bfloat16(fmaxf(a.w + bv.w, 0.f));
        ((s16x4*)outv)[i4] = u.p;
    } else if constexpr (MODE == 1) {
        const int   T   = *Tp;
        const float be1 = 1.f / (1.f + expf(-b_taus[0]));
        const float be2 = 1.f / (1.f + expf(-b_taus[1]));
        const float be3 = 1.f / (1.f + expf(-b_taus[2]));
        float y[4] = {a.x, a.y, a.z, a.w};
        float bb[4] = {bv.x, bv.y, bv.z, bv.w};
        union { s16x4 p; __hip_bfloat16 h[4]; } u;
        #pragma unroll
        for (int c = 0; c < 4; ++c) {
            float p1 = 1.f, s2 = 0.f, za = 0.f;
            for (int t = 0; t < T; ++t) {
                p1 *= be1;
                const float d2 = fmaxf(fmaf(1.f - p1, y[c], bb[c]), 0.f);
                s2 = be2 * s2 + (1.f - be2) * d2;
                za = be3 * za + (1.f - be3) * s2;
            }
            u.h[c] = __float2bfloat16(za);
        }
        ((s16x4*)outv)[i4] = u.p;
    } else {
        const int   T   = *Tp;
        const float be3 = 1.f / (1.f + expf(-b_taus[2]));
        float g = 0.f;
        for (int t = 0; t < T; ++t) g = be3 * g + (1.f - be3);   // 1 - beta3^T
        float4 o;
        o.x = a.x + g * bv.x;
        o.y = a.y + g * bv.y;
        o.z = a.z + g * bv.z;
        o.w = a.w + g * bv.w;
        ((float4*)outv)[i4] = o;
    }
}

extern "C" void kernel_launch(void* const* d_in, const int* in_sizes, int n_in,
                              void* d_out, int out_size, void* d_ws, size_t ws_size,
                              hipStream_t stream) {
    const float* x      = (const float*)d_in[0];
    const float* W1     = (const float*)d_in[1];
    const float* b1     = (const float*)d_in[2];
    const float* W2     = (const float*)d_in[3];
    const float* b2     = (const float*)d_in[4];
    const float* W3     = (const float*)d_in[5];
    const float* b3     = (const float*)d_in[6];
    const float* b_taus = (const float*)d_in[7];
    const int*   Tp     = (const int*)d_in[8];

    const int B = 1024, DIN = 2048, H1 = 4096, H2 = 4096, DOUT = 1024;
    const long MB = 1024 * 1024;

    // Workspace arena, 120 MB peak, with aliasing:
    //   [0 .. 64MB)  "region": xb@0(4MB), W1b@4MB(16MB), P1@20MB(32MB)   -- phase 1
    //                 then P2@0(64MB)                                     -- phase 2
    //                 then P3@0(32MB)                                     -- phase 3
    //   [64 .. 96MB)  W2b   [96 .. 104MB) W3b   [104 .. 112MB) D1b   [112 .. 120MB) Sb
    char* ws = (char*)d_ws;
    __hip_bfloat16* xb  = (__hip_bfloat16*)(ws + 0);
    __hip_bfloat16* W1b = (__hip_bfloat16*)(ws + 4 * MB);
    float*          P1  = (float*)         (ws + 20 * MB);
    float*          P2  = (float*)         (ws + 0);
    float*          P3  = (float*)         (ws + 0);
    __hip_bfloat16* W2b = (__hip_bfloat16*)(ws + 64 * MB);
    __hip_bfloat16* W3b = (__hip_bfloat16*)(ws + 96 * MB);
    __hip_bfloat16* D1b = (__hip_bfloat16*)(ws + 104 * MB);
    __hip_bfloat16* Sb  = (__hip_bfloat16*)(ws + 112 * MB);

    // 1. Cast all fp32 inputs to bf16 (one launch, exact cover: 7,864,320 float4s)
    cast_all_k<<<dim3(30720), dim3(256), 0, stream>>>(x, W1, W2, W3, xb, W1b, W2b, W3b);

    // 2. Layer 1: P1 = split-K(x @ W1^T), S=2   (512 blocks, 2/CU)
    gemm_btk<<<dim3(H1 / 128, B / 128, 2), 256, 0, stream>>>(xb, W1b, P1, B, H1, DIN / 2);
    // 3. D1 = relu(sum P1 + b1), bf16
    reduce_k<0><<<dim3(4096), 256, 0, stream>>>(P1, 2, (void*)D1b, (long)B * H1, H1, b1, nullptr, nullptr);

    // 4. Layer 2: P2 = split-K(D1 @ W2^T), S=4  (1024 blocks, 4/CU)
    gemm_btk<<<dim3(H2 / 128, B / 128, 4), 256, 0, stream>>>(D1b, W2b, P2, B, H2, H1 / 4);
    // 5. Z = T-collapse(sum P2, b2), bf16
    reduce_k<1><<<dim3(4096), 256, 0, stream>>>(P2, 4, (void*)Sb, (long)B * H2, H2, b2, b_taus, Tp);

    // 6. Layer 3: P3 = split-K(Z @ W3^T), S=8   (512 blocks, 2/CU)
    gemm_btk<<<dim3(DOUT / 128, B / 128, 8), 256, 0, stream>>>(Sb, W3b, P3, B, DOUT, H2 / 8);
    // 7. out = sum P3 + (1-beta3^T)*b3, fp32
    reduce_k<2><<<dim3(1024), 256, 0, stream>>>(P3, 8, d_out, (long)B * DOUT, DOUT, b3, b_taus, Tp);
}